// Round 7
// baseline (442.651 us; speedup 1.0000x reference)
//
#include <hip/hip_runtime.h>
#include <hip/hip_bf16.h>

typedef __hip_bfloat16 bf16;
typedef __attribute__((ext_vector_type(8))) short short8;
typedef __attribute__((ext_vector_type(4))) short short4v;
typedef __attribute__((ext_vector_type(4))) float floatx4;
typedef __attribute__((ext_vector_type(16))) float floatx16;

#define Bn 8
#define Cc 128
#define Hh 128
#define Wl 128
#define HW (Hh*Wl)
#define NT (Bn*HW)   // 131072 tokens
#define REG 8388608  // elements per qkv phase-buffer (16 MiB bf16)

// q is pre-scaled by 0.25*log2(e) at the qkv scatter, so softmax uses exp2 directly.
#define QSCALE 0.36067376022224085f
#if __has_builtin(__builtin_amdgcn_exp2f)
#define EXP2(x) __builtin_amdgcn_exp2f(x)
#else
#define EXP2(x) __expf((x)*0.69314718055994531f)
#endif

__device__ __forceinline__ float b2f(bf16 v){ return __bfloat162float(v); }
__device__ __forceinline__ bf16  f2b(float v){ return __float2bfloat16(v); }

// async global -> LDS, 16B per lane. LDS dest must be wave-uniform base (+lane*16 implicit).
#define GL16(gp, lp) __builtin_amdgcn_global_load_lds( \
    (__attribute__((address_space(1))) unsigned int*)(gp), \
    (__attribute__((address_space(3))) unsigned int*)(lp), 16, 0, 0)

// ---------------- all weight transposes in one launch ----------------
__global__ __launch_bounds__(256) void transpose_all(const float* __restrict__ wqkv,
                                                     const float* __restrict__ proj_w,
                                                     const float* __restrict__ fc1_w,
                                                     const float* __restrict__ fc2_w,
                                                     bf16* __restrict__ qkvT,
                                                     bf16* __restrict__ projT,
                                                     bf16* __restrict__ fc1T,
                                                     bf16* __restrict__ fc2T){
  int idx = blockIdx.x*256 + threadIdx.x;
  const float* src; bf16* dst; int K, N;
  if(idx < 49152){ src=wqkv; dst=qkvT; K=128; N=384; }
  else if(idx < 65536){ idx -= 49152; src=proj_w; dst=projT; K=128; N=128; }
  else if(idx < 131072){ idx -= 65536; src=fc1_w; dst=fc1T; K=128; N=512; }
  else { idx -= 131072; src=fc2_w; dst=fc2T; K=512; N=128; }
  int n = idx % N, k = idx / N;
  dst[(size_t)n*K + k] = f2b(src[idx]);
}

// ---------------- depthwise 3x3 conv + bias + residual -> channel-last fp32 ----------------
__global__ __launch_bounds__(256) void conv_kernel(const float* __restrict__ x,
                                                   const float* __restrict__ cw,
                                                   const float* __restrict__ cb,
                                                   float* __restrict__ xt){
  __shared__ float tile[16][132];
  int blk = blockIdx.x;              // ((b*8 + cg)*128 + h)
  int h = blk & 127; int t = blk >> 7;
  int cg = t & 7;    int b = t >> 3;
  int w4 = threadIdx.x & 31;
  int ci = threadIdx.x >> 5;
  int w0 = w4*4;
#pragma unroll
  for(int cc=0; cc<2; cc++){
    int c = cg*16 + ci*2 + cc;
    const float* xp = x + ((size_t)(b*Cc + c))*HW;
    float wg[9];
#pragma unroll
    for(int i=0;i<9;i++) wg[i] = cw[c*9+i];
    float4 rowv[3]; float lf[3], rt[3];
#pragma unroll
    for(int r=0;r<3;r++){
      int hh = h-1+r;
      float4 v = {0.f,0.f,0.f,0.f};
      if(hh>=0 && hh<Hh) v = *(const float4*)(xp + hh*Wl + w0);
      rowv[r] = v;
      float l = __shfl_up(v.w, 1, 32);
      float rr = __shfl_down(v.x, 1, 32);
      lf[r] = (w4==0)  ? 0.f : l;
      rt[r] = (w4==31) ? 0.f : rr;
    }
    float acc0 = cb[c], acc1 = cb[c], acc2 = cb[c], acc3 = cb[c];
#pragma unroll
    for(int r=0;r<3;r++){
      float4 v = rowv[r];
      acc0 += wg[r*3+0]*lf[r] + wg[r*3+1]*v.x + wg[r*3+2]*v.y;
      acc1 += wg[r*3+0]*v.x   + wg[r*3+1]*v.y + wg[r*3+2]*v.z;
      acc2 += wg[r*3+0]*v.y   + wg[r*3+1]*v.z + wg[r*3+2]*v.w;
      acc3 += wg[r*3+0]*v.z   + wg[r*3+1]*v.w + wg[r*3+2]*rt[r];
    }
    acc0 += rowv[1].x; acc1 += rowv[1].y; acc2 += rowv[1].z; acc3 += rowv[1].w;
    float4 o = {acc0, acc1, acc2, acc3};
    *(float4*)&tile[ci*2+cc][w0] = o;
  }
  __syncthreads();
  const size_t obase = ((size_t)b*HW + (size_t)h*Wl)*Cc + cg*16;
#pragma unroll
  for(int i=0;i<8;i++){
    int idx = i*256 + threadIdx.x;
    int c2 = idx & 15, w2 = idx >> 4;
    xt[obase + (size_t)w2*Cc + c2] = tile[c2][w2];
  }
}

// ---------------- LayerNorm over C=128, one wave per token ----------------
__global__ __launch_bounds__(256) void ln_kernel(const float* __restrict__ xt,
                                                 const float* __restrict__ wv,
                                                 const float* __restrict__ bv,
                                                 bf16* __restrict__ xn){
  int tok  = blockIdx.x*4 + (threadIdx.x>>6);
  int lane = threadIdx.x & 63;
  const float* row = xt + (size_t)tok*Cc;
  float v0 = row[lane], v1 = row[lane+64];
  float s = v0+v1;
#pragma unroll
  for(int off=32; off; off>>=1) s += __shfl_down(s, off, 64);
  s = __shfl(s, 0, 64);
  float m = s * (1.0f/128.0f);
  float d0 = v0-m, d1 = v1-m;
  float vs = d0*d0 + d1*d1;
#pragma unroll
  for(int off=32; off; off>>=1) vs += __shfl_down(vs, off, 64);
  vs = __shfl(vs, 0, 64);
  float rstd = rsqrtf(vs*(1.0f/128.0f) + 1e-5f);
  bf16* orow = xn + (size_t)tok*Cc;
  orow[lane]    = f2b(d0*rstd*wv[lane]    + bv[lane]);
  orow[lane+64] = f2b(d1*rstd*wv[lane+64] + bv[lane+64]);
}

// ---------------- MFMA bf16 GEMM (global_load_lds staging, dbuf, XCD swizzle) ----------------
// EPI 0: qkv -> scatter into 6 head-major attention buffers (outb = base of qL..vG)
// EPI 2: +bias, xt += ls*v
template<int EPI>
__global__ __launch_bounds__(256) void mfma_gemm(const bf16* __restrict__ A,
                                                 const bf16* __restrict__ Wt,
                                                 const float* __restrict__ bias,
                                                 bf16* __restrict__ outb,
                                                 float* __restrict__ xt,
                                                 const float* __restrict__ ls,
                                                 int N, int K){
  __shared__ short As[2][128*32];
  __shared__ short Bs[2][64*32];
  const int tid  = threadIdx.x;
  const int lane = tid & 63;
  const int w    = tid >> 6;

  // XCD-chunked swizzle: all n-blocks of one m-tile land on the same XCD (consecutive t)
  const int nwg = gridDim.x * gridDim.y;
  const int lin = blockIdx.y * gridDim.x + blockIdx.x;
  const int t   = (lin & 7) * (nwg >> 3) + (lin >> 3);
  const int m0  = (t / gridDim.x) * 128;
  const int n0  = (t % gridDim.x) * 64;

  // pre-swizzled global source addresses so linear LDS (= fragment order) is correct:
  // lidx -> row = (lidx>>6)*16 + (lidx&15), kchunk = (lidx>>4)&3
  const int l1 = tid + 256;
  const bf16* gA0 = A  + (size_t)(m0 + ((tid>>6)<<4) + (tid&15))*K + (((tid>>4)&3)<<3);
  const bf16* gA1 = A  + (size_t)(m0 + ((l1 >>6)<<4) + (l1 &15))*K + (((l1 >>4)&3)<<3);
  const bf16* gB  = Wt + (size_t)(n0 + ((tid>>6)<<4) + (tid&15))*K + (((tid>>4)&3)<<3);
  // wave-uniform LDS dest bases (shorts)
  const int ldsA0 = w*512;           // chunk 0: lidx = w*64+lane
  const int ldsA1 = 2048 + w*512;    // chunk 1: lidx = 256 + w*64+lane
  const int ldsB  = w*512;

  floatx4 acc[4][2];
#pragma unroll
  for(int i=0;i<4;i++)
#pragma unroll
    for(int j=0;j<2;j++) acc[i][j] = (floatx4){0.f,0.f,0.f,0.f};

  const int nk = K >> 5;
  // prologue: stage k-step 0 into buf 0
  GL16(gA0, &As[0][ldsA0]);
  GL16(gA1, &As[0][ldsA1]);
  GL16(gB , &Bs[0][ldsB ]);
  __syncthreads();

  int cur = 0;
  for(int it=0; it<nk; ++it){
    if(it+1 < nk){
      const int kn = (it+1) << 5;
      GL16(gA0 + kn, &As[cur^1][ldsA0]);
      GL16(gA1 + kn, &As[cur^1][ldsA1]);
      GL16(gB  + kn, &Bs[cur^1][ldsB ]);
    }
    short8 af[4], bfr[2];
#pragma unroll
    for(int mt=0;mt<4;mt++) af[mt] = *(short8*)&As[cur][(((w&1)*4+mt)*64 + lane)*8];
#pragma unroll
    for(int nt=0;nt<2;nt++) bfr[nt] = *(short8*)&Bs[cur][(((w>>1)*2+nt)*64 + lane)*8];
#pragma unroll
    for(int mt=0;mt<4;mt++)
#pragma unroll
      for(int nt=0;nt<2;nt++)
        acc[mt][nt] = __builtin_amdgcn_mfma_f32_16x16x32_bf16(af[mt], bfr[nt], acc[mt][nt], 0, 0, 0);
    __syncthreads();   // drains vmcnt (prefetch landed) + all waves done reading buf cur
    cur ^= 1;
  }

#pragma unroll
  for(int mt=0;mt<4;mt++){
#pragma unroll
    for(int nt=0;nt<2;nt++){
#pragma unroll
      for(int r=0;r<4;r++){
        int row = m0 + (w&1)*64 + mt*16 + ((lane>>4))*4 + r;
        int col = n0 + (w>>1)*32 + nt*16 + (lane&15);
        float v = acc[mt][nt][r];
        if(EPI==0){
          // scatter to attention layout: reg 0..5 = qL,qG,kL,kG,vL,vG
          int reg = col >> 6;
          int head = (col >> 4) & 3;
          int ch = col & 15;
          int b = row >> 14, h = (row >> 7) & 127, ww = row & 127;
          if(reg < 2) v *= QSCALE;   // fold softmax scale*log2e into q
          size_t didx;
          if(!(reg & 1)){
            int inst = ((b*16 + (h>>3))*16 + (ww>>3))*4 + head;
            int pos = (h&7)*8 + (ww&7);
            didx = ((size_t)inst*64 + pos)*16 + ch;
          } else {
            int inst = ((b*8 + (h&7))*8 + (ww&7))*4 + head;
            int pos = (h>>3)*16 + (ww>>3);
            didx = ((size_t)inst*256 + pos)*16 + ch;
          }
          outb[(size_t)reg*REG + didx] = f2b(v);
        } else if(EPI==2){
          v += bias[col];
          xt[(size_t)row*128 + col] += ls[col]*v;
        }
      }
    }
  }
}

// ---------------- fused MLP v4: 4 waves, 16 chunks of 32, dbuf staging, 3 blocks/CU ----
// out = bf16(xt + ls2 * (gelu(xn@W1 + b1) @ W2 + b2))
// Block = 128 tokens (wave owns 32 rows). N1=512 in 16 chunks of 32. Per chunk:
// issue next chunk's weight staging first, compute current from LDS, one barrier.
// LDS: W1 dbuf 16KB | W2 dbuf 16KB | per-wave h tiles 10KB = 42KB -> 3 blocks/CU (12 waves).
// In-place: outb may alias A (wave reads only its own 32 rows into regs before writing them).
__global__ __launch_bounds__(256) void fused_mlp(const bf16* A,                 // xn2 [NT][128]
                                                 const bf16* __restrict__ W1,   // fc1T [512][128]
                                                 const float* __restrict__ b1,
                                                 const bf16* __restrict__ W2,   // fc2T [128][512]
                                                 const float* __restrict__ b2,
                                                 const float* __restrict__ xt,
                                                 const float* __restrict__ ls,
                                                 bf16* outb){
  extern __shared__ short lds[];
  // layout (shorts): W1s[2][4096] | W2s[2][4096] | hs[4][1280]
  const int W1OFF = 0, W2OFF = 8192, HSOFF = 16384;
  const int tid = threadIdx.x, lane = tid & 63, w = tid >> 6;
  const int n16 = lane & 15, quad = lane >> 4;
  const int lin = blockIdx.x;
  const int t = (lin & 7)*128 + (lin >> 3);   // 1024 blocks, XCD-chunked
  const int mw = t*128 + w*32;

  // stage W1/W2 chunk nc (32 n1) into buffer buf. Frag layout: [fid][lane*8].
  // W1 fid = nt*4+ks (nt<2, ks<4); W2 fid = nt2 (8 frags, k-slice = this chunk).
  auto stage = [&](int nc, int buf){
    const bf16* W1c = W1 + (size_t)nc*32*128;
#pragma unroll
    for(int p=0;p<2;p++){
      int fid = p*4 + w;                      // wave-uniform 0..7
      int nt = fid >> 2, ks = fid & 3;
      GL16(W1c + (size_t)(nt*16 + n16)*128 + ks*32 + quad*8, &lds[W1OFF + buf*4096 + fid*512]);
      GL16(W2 + (size_t)(fid*16 + n16)*512 + nc*32 + quad*8, &lds[W2OFF + buf*4096 + fid*512]);
    }
  };

  // A (this wave's 32 rows) into registers
  short8 areg[2][4];
#pragma unroll
  for(int mt=0;mt<2;mt++)
#pragma unroll
    for(int ks=0;ks<4;ks++)
      areg[mt][ks] = *(const short8*)(A + (size_t)(mw + mt*16 + n16)*128 + ks*32 + quad*8);

  floatx4 acc2[2][8];
#pragma unroll
  for(int i=0;i<2;i++)
#pragma unroll
    for(int j=0;j<8;j++) acc2[i][j] = (floatx4){0.f,0.f,0.f,0.f};

  short* hw = &lds[HSOFF + w*1280];   // [32 m][32 n + 8 pad]

  stage(0, 0);
  __syncthreads();                    // buf0 ready (barrier drains vmcnt)

  for(int nc=0; nc<16; ++nc){
    const int cur = nc & 1;
    if(nc+1 < 16) stage(nc+1, cur^1); // issue next chunk's loads BEFORE compute

    // GEMM1: h[32][32] = A[32][128] x W1c[128][32]
    const short* W1b = &lds[W1OFF + cur*4096];
    floatx4 acc1[2][2];
#pragma unroll
    for(int i=0;i<2;i++)
#pragma unroll
      for(int j=0;j<2;j++) acc1[i][j] = (floatx4){0.f,0.f,0.f,0.f};
#pragma unroll
    for(int ks=0;ks<4;ks++){
#pragma unroll
      for(int nt=0;nt<2;nt++){
        short8 bfr = *(const short8*)&W1b[(nt*4+ks)*512 + lane*8];
#pragma unroll
        for(int mt=0;mt<2;mt++)
          acc1[mt][nt] = __builtin_amdgcn_mfma_f32_16x16x32_bf16(areg[mt][ks], bfr, acc1[mt][nt], 0, 0, 0);
      }
    }

    // bias + GELU (tanh form, exp2 + fast rcp) -> bf16 -> wave-private LDS
#pragma unroll
    for(int nt=0;nt<2;nt++){
      float bb = b1[nc*32 + nt*16 + n16];
#pragma unroll
      for(int mt=0;mt<2;mt++){
#pragma unroll
        for(int r=0;r<4;r++){
          float v = acc1[mt][nt][r] + bb;
          float u = v*v;
          float e = EXP2(v*__fmaf_rn(u, 0.044715f, 1.0f)*(-2.3022127f));
          float g = v*__builtin_amdgcn_rcpf(1.0f + e);
          bf16 gb = f2b(g);
          hw[(mt*16 + quad*4 + r)*40 + nt*16 + n16] = *(short*)&gb;
        }
      }
    }

    // GEMM2 partial: acc2 += h[32][32] x W2c[32][128] (k=32 = one MFMA depth)
    const short* W2b = &lds[W2OFF + cur*4096];
    short8 ha[2];
#pragma unroll
    for(int mt=0;mt<2;mt++) ha[mt] = *(short8*)&hw[(mt*16 + n16)*40 + quad*8];
#pragma unroll
    for(int nt2=0;nt2<8;nt2++){
      short8 bf2 = *(const short8*)&W2b[nt2*512 + lane*8];
#pragma unroll
      for(int mt=0;mt<2;mt++)
        acc2[mt][nt2] = __builtin_amdgcn_mfma_f32_16x16x32_bf16(ha[mt], bf2, acc2[mt][nt2], 0, 0, 0);
    }

    __syncthreads();   // next buf staged (vmcnt drained) + all waves done reading cur
  }

  // epilogue: out = bf16(xt + ls2*(acc2 + b2))
#pragma unroll
  for(int nt2=0;nt2<8;nt2++){
    int col = nt2*16 + n16;
    float bb = b2[col], lsv = ls[col];
#pragma unroll
    for(int mt=0;mt<2;mt++){
#pragma unroll
      for(int r=0;r<4;r++){
        int row = mw + mt*16 + quad*4 + r;
        float v = acc2[mt][nt2][r] + bb;
        float rr = xt[(size_t)row*128 + col] + lsv*v;
        outb[(size_t)row*128 + col] = f2b(rr);
      }
    }
  }
}

// ---------------- local attention: blk = winid*4 + head, L=64 ----------------
// q pre-scaled by QSCALE -> base-2 softmax with max subtraction.
__global__ __launch_bounds__(256) void attn_local2(const bf16* __restrict__ qL,
                                                   const bf16* __restrict__ kL,
                                                   const bf16* __restrict__ vL,
                                                   bf16* __restrict__ a){
  __shared__ short vt[16*72];      // V^T [16 ch][64 tok + 8 pad]
  __shared__ short pb[4][16*72];   // per-wave P
  const int tid = threadIdx.x;
  const int w = tid >> 6, lane = tid & 63;
  const int n16 = lane & 15, quad = lane >> 4;
  const int blk = blockIdx.x;
  const int head = blk & 3, winid = blk >> 2;
  const bf16* Qb = qL + (size_t)blk*1024;
  const bf16* Kb = kL + (size_t)blk*1024;
  const bf16* Vb = vL + (size_t)blk*1024;

  if(tid < 128){
    int tok = tid >> 1, u = tid & 1;
    short8 v = *(const short8*)(Vb + tok*16 + u*8);
#pragma unroll
    for(int i=0;i<8;i++) vt[(u*8+i)*72 + tok] = ((short*)&v)[i];
  }
  __syncthreads();

  const int qt = w;
  short8 qf = {0,0,0,0,0,0,0,0};
  if(quad < 2) qf = *(const short8*)(Qb + (qt*16+n16)*16 + quad*8);

  floatx4 sf[4];
#pragma unroll
  for(int kt=0; kt<4; kt++){
    short8 kf = {0,0,0,0,0,0,0,0};
    if(quad < 2) kf = *(const short8*)(Kb + (kt*16+n16)*16 + quad*8);
    floatx4 z = (floatx4){0.f,0.f,0.f,0.f};
    sf[kt] = __builtin_amdgcn_mfma_f32_16x16x32_bf16(qf, kf, z, 0, 0, 0);
  }

  float mx[4] = {-1e30f,-1e30f,-1e30f,-1e30f};
#pragma unroll
  for(int kt=0; kt<4; kt++)
#pragma unroll
    for(int r=0;r<4;r++) mx[r] = fmaxf(mx[r], sf[kt][r]);
#pragma unroll
  for(int r=0;r<4;r++){
    mx[r] = fmaxf(mx[r], __shfl_xor(mx[r], 1, 64));
    mx[r] = fmaxf(mx[r], __shfl_xor(mx[r], 2, 64));
    mx[r] = fmaxf(mx[r], __shfl_xor(mx[r], 4, 64));
    mx[r] = fmaxf(mx[r], __shfl_xor(mx[r], 8, 64));
    mx[r] = -mx[r];
  }
  float l[4] = {0.f,0.f,0.f,0.f};
#pragma unroll
  for(int kt=0; kt<4; kt++){
#pragma unroll
    for(int r=0;r<4;r++){
      float p = EXP2(sf[kt][r] + mx[r]);
      l[r] += p;
      bf16 pbv = f2b(p);
      pb[w][(quad*4+r)*72 + kt*16 + n16] = *(short*)&pbv;
    }
  }
#pragma unroll
  for(int r=0;r<4;r++){
    l[r] += __shfl_xor(l[r], 1, 64);
    l[r] += __shfl_xor(l[r], 2, 64);
    l[r] += __shfl_xor(l[r], 4, 64);
    l[r] += __shfl_xor(l[r], 8, 64);
  }

  floatx4 of = (floatx4){0.f,0.f,0.f,0.f};
#pragma unroll
  for(int kb=0; kb<2; kb++){
    short8 pf = *(short8*)&pb[w][n16*72 + kb*32 + quad*8];
    short8 vfb = *(short8*)&vt[n16*72 + kb*32 + quad*8];
    of = __builtin_amdgcn_mfma_f32_16x16x32_bf16(pf, vfb, of, 0, 0, 0);
  }

  const int wj = winid & 15, wi = (winid >> 4) & 15, b = winid >> 8;
  const int ooff = head*16;
#pragma unroll
  for(int r=0;r<4;r++){
    int pos = qt*16 + quad*4 + r;
    int h = wi*8 + (pos>>3), ww = wj*8 + (pos&7);
    size_t t = (size_t)b*HW + (size_t)h*Wl + ww;
    a[t*Cc + ooff + n16] = f2b(of[r] / l[r]);
  }
}

// ---------------- grid attention v2: swapped 32x32x16 QK^T, no-max base-2 softmax ----------------
// blk = ginst*4 + head, L=256. Each wave: 2 q-tiles of 32 rows; K in 2 chunks of 128.
__global__ __launch_bounds__(256) void attn_grid2(const bf16* __restrict__ qG,
                                                  const bf16* __restrict__ kG,
                                                  const bf16* __restrict__ vG,
                                                  bf16* __restrict__ a){
  __shared__ short vt[16*264];       // V^T [16 ch][256 tok + 8 pad]
  __shared__ short pb[4][32*136];    // per-wave P [32 q][128 k + 8 pad]
  const int tid = threadIdx.x;
  const int w = tid >> 6, lane = tid & 63;
  const int n16 = lane & 15, quad = lane >> 4;
  const int q32 = lane & 31, hb = lane >> 5;
  const int blk = blockIdx.x;
  const int head = blk & 3, ginst = blk >> 2;
  const bf16* Qb = qG + (size_t)blk*4096;
  const bf16* Kb = kG + (size_t)blk*4096;
  const bf16* Vb = vG + (size_t)blk*4096;

#pragma unroll
  for(int it=0; it<2; it++){
    int chunk = it*256 + tid;
    int tok = chunk >> 1, u = chunk & 1;
    short8 v = *(const short8*)(Vb + tok*16 + u*8);
#pragma unroll
    for(int i=0;i<8;i++) vt[(u*8+i)*264 + tok] = ((short*)&v)[i];
  }
  __syncthreads();

  const int sj = ginst & 7, si = (ginst >> 3) & 7, b = ginst >> 6;
  const int ooff = 64 + head*16;
  short* pbw = pb[w];
  const floatx16 Z16 = {0.f,0.f,0.f,0.f,0.f,0.f,0.f,0.f,0.f,0.f,0.f,0.f,0.f,0.f,0.f,0.f};

#pragma unroll
  for(int qi=0; qi<2; qi++){
    const int q0 = w*64 + qi*32;
    const short8 qf = *(const short8*)(Qb + (size_t)(q0 + q32)*16 + hb*8);
    float l_acc = 0.f;
    floatx4 of0 = (floatx4){0.f,0.f,0.f,0.f};
    floatx4 of1 = (floatx4){0.f,0.f,0.f,0.f};
#pragma unroll
    for(int kc=0; kc<2; kc++){
#pragma unroll
      for(int kt=0; kt<4; kt++){
        short8 kf = *(const short8*)(Kb + (size_t)(kc*128 + kt*32 + q32)*16 + hb*8);
        // swapped: D[k][q], col=lane&31=q, row k = (reg&3)+8*(reg>>2)+4*hb (+32*kt)
        floatx16 s = __builtin_amdgcn_mfma_f32_32x32x16_bf16(kf, qf, Z16, 0, 0, 0);
#pragma unroll
        for(int g=0; g<4; g++){
          float p0 = EXP2(s[4*g+0]);
          float p1 = EXP2(s[4*g+1]);
          float p2 = EXP2(s[4*g+2]);
          float p3 = EXP2(s[4*g+3]);
          l_acc += (p0+p1)+(p2+p3);
          short4v pk = { (short)__bfloat16_as_ushort(f2b(p0)),
                         (short)__bfloat16_as_ushort(f2b(p1)),
                         (short)__bfloat16_as_ushort(f2b(p2)),
                         (short)__bfloat16_as_ushort(f2b(p3)) };
          *(short4v*)&pbw[q32*136 + kt*32 + g*8 + hb*4] = pk;
        }
      }
      // PV partial accumulate over this 128-wide k-chunk
#pragma unroll
      for(int kb=0; kb<4; kb++){
        short8 vf  = *(short8*)&vt[n16*264 + kc*128 + kb*32 + quad*8];
        short8 pf0 = *(short8*)&pbw[n16*136 + kb*32 + quad*8];
        of0 = __builtin_amdgcn_mfma_f32_16x16x32_bf16(pf0, vf, of0, 0, 0, 0);
        short8 pf1 = *(short8*)&pbw[(16+n16)*136 + kb*32 + quad*8];
        of1 = __builtin_amdgcn_mfma_f32_16x16x32_bf16(pf1, vf, of1, 0, 0, 0);
      }
    }
    l_acc += __shfl_xor(l_acc, 32, 64);
#pragma unroll
    for(int hf=0; hf<2; hf++){
      floatx4 of = hf ? of1 : of0;
#pragma unroll
      for(int r=0;r<4;r++){
        float lr = __shfl(l_acc, hf*16 + quad*4 + r, 64);
        int pos = q0 + hf*16 + quad*4 + r;
        int h = (pos>>4)*8 + si, ww = (pos&15)*8 + sj;
        size_t t = (size_t)b*HW + (size_t)h*Wl + ww;
        a[t*Cc + ooff + n16] = f2b(of[r] / lr);
      }
    }
  }
}

// ---------------- (B, HW, C) -> (B, C, HW) transpose, bf16 -> fp32 out ----------------
__global__ __launch_bounds__(256) void transpose_kernel(const bf16* __restrict__ xf,
                                                        float* __restrict__ out){
  __shared__ bf16 tile[32][33];
  int t0 = blockIdx.x*32, c0 = blockIdx.y*32, b = blockIdx.z;
  int x = threadIdx.x, y = threadIdx.y;   // 32, 8
  const bf16* src = xf + (size_t)b*HW*Cc;
  float* dst = out + (size_t)b*Cc*HW;
#pragma unroll
  for(int i=0;i<4;i++)
    tile[y*4+i][x] = src[(size_t)(t0 + y*4+i)*Cc + c0 + x];
  __syncthreads();
#pragma unroll
  for(int i=0;i<4;i++)
    dst[(size_t)(c0 + y*4+i)*HW + t0 + x] = b2f(tile[x][y*4+i]);
}

extern "C" void kernel_launch(void* const* d_in, const int* in_sizes, int n_in,
                              void* d_out, int out_size, void* d_ws, size_t ws_size,
                              hipStream_t stream) {
  const float* x       = (const float*)d_in[0];
  const float* conv_w  = (const float*)d_in[1];
  const float* conv_b  = (const float*)d_in[2];
  const float* norm1_w = (const float*)d_in[3];
  const float* norm1_b = (const float*)d_in[4];
  const float* wqkv    = (const float*)d_in[5];
  const float* proj_w  = (const float*)d_in[6];
  const float* proj_b  = (const float*)d_in[7];
  const float* norm2_w = (const float*)d_in[8];
  const float* norm2_b = (const float*)d_in[9];
  const float* fc1_w   = (const float*)d_in[10];
  const float* fc1_b   = (const float*)d_in[11];
  const float* fc2_w   = (const float*)d_in[12];
  const float* fc2_b   = (const float*)d_in[13];
  const float* ls1     = (const float*)d_in[14];
  const float* ls2     = (const float*)d_in[15];
  float* out = (float*)d_out;

  char* ws = (char*)d_ws;
  float* xt = (float*)ws;                                        // 64 MiB fp32 residual
  bf16*  sh = (bf16*)(ws + (size_t)NT*Cc*4);                     // 32 MiB: xn -> a -> xn2 -> xt_final
  bf16*  qh = (bf16*)(ws + (size_t)NT*Cc*4 + (size_t)NT*Cc*2);   // 128 MiB: qkv buffers
  bf16*  wt = (bf16*)(ws + (size_t)NT*Cc*4 + (size_t)NT*Cc*2 + (size_t)NT*512*2);
  bf16* qkvT = wt;            // 384 x 128
  bf16* projT= wt + 49152;    // 128 x 128
  bf16* fc1T = wt + 65536;    // 512 x 128
  bf16* fc2T = wt + 131072;   // 128 x 512

  transpose_all<<<196608/256, 256, 0, stream>>>(wqkv, proj_w, fc1_w, fc2_w,
                                                qkvT, projT, fc1T, fc2T);
  conv_kernel<<<Bn*8*Hh, 256, 0, stream>>>(x, conv_w, conv_b, xt);
  ln_kernel<<<NT/4, 256, 0, stream>>>(xt, norm1_w, norm1_b, sh);
  // qkv GEMM scatters into qL,qG,kL,kG,vL,vG (6 x 16 MiB at qh)
  mfma_gemm<0><<<dim3(384/64, NT/128), 256, 0, stream>>>(sh, qkvT, nullptr, qh, nullptr, nullptr, 384, 128);
  attn_grid2<<<2048, 256, 0, stream>>>(qh + (size_t)1*REG, qh + (size_t)3*REG, qh + (size_t)5*REG, sh);
  attn_local2<<<8192, 256, 0, stream>>>(qh + (size_t)0*REG, qh + (size_t)2*REG, qh + (size_t)4*REG, sh);
  mfma_gemm<2><<<dim3(128/64, NT/128), 256, 0, stream>>>(sh, projT, proj_b, nullptr, xt, ls1, 128, 128);
  ln_kernel<<<NT/4, 256, 0, stream>>>(xt, norm2_w, norm2_b, sh);
  // fused MLP: 256 threads/block, 128 tokens/block, 43008B dynamic LDS -> 3 blocks/CU
  fused_mlp<<<NT/128, 256, 43008, stream>>>(sh, fc1T, fc1_b, fc2T, fc2_b, xt, ls2, sh);
  transpose_kernel<<<dim3(HW/32, Cc/32, Bn), dim3(32,8), 0, stream>>>(sh, out);
}

// Round 9
// 401.685 us; speedup vs baseline: 1.1020x; 1.1020x over previous
//
#include <hip/hip_runtime.h>
#include <hip/hip_bf16.h>

typedef __hip_bfloat16 bf16;
typedef __attribute__((ext_vector_type(8))) short short8;
typedef __attribute__((ext_vector_type(4))) short short4v;
typedef __attribute__((ext_vector_type(4))) float floatx4;
typedef __attribute__((ext_vector_type(16))) float floatx16;

#define Bn 8
#define Cc 128
#define Hh 128
#define Wl 128
#define HW (Hh*Wl)
#define NT (Bn*HW)   // 131072 tokens
#define REG 8388608  // elements per qkv phase-buffer (16 MiB bf16)

// q is pre-scaled by 0.25*log2(e) at the qkv scatter, so softmax uses exp2 directly.
#define QSCALE 0.36067376022224085f
#if __has_builtin(__builtin_amdgcn_exp2f)
#define EXP2(x) __builtin_amdgcn_exp2f(x)
#else
#define EXP2(x) __expf((x)*0.69314718055994531f)
#endif

__device__ __forceinline__ float b2f(bf16 v){ return __bfloat162float(v); }
__device__ __forceinline__ bf16  f2b(float v){ return __float2bfloat16(v); }

// async global -> LDS, 16B per lane. LDS dest must be wave-uniform base (+lane*16 implicit).
#define GL16(gp, lp) __builtin_amdgcn_global_load_lds( \
    (__attribute__((address_space(1))) unsigned int*)(gp), \
    (__attribute__((address_space(3))) unsigned int*)(lp), 16, 0, 0)

// ---------------- all weight transposes in one launch ----------------
__global__ __launch_bounds__(256) void transpose_all(const float* __restrict__ wqkv,
                                                     const float* __restrict__ proj_w,
                                                     const float* __restrict__ fc1_w,
                                                     const float* __restrict__ fc2_w,
                                                     bf16* __restrict__ qkvT,
                                                     bf16* __restrict__ projT,
                                                     bf16* __restrict__ fc1T,
                                                     bf16* __restrict__ fc2T){
  int idx = blockIdx.x*256 + threadIdx.x;
  const float* src; bf16* dst; int K, N;
  if(idx < 49152){ src=wqkv; dst=qkvT; K=128; N=384; }
  else if(idx < 65536){ idx -= 49152; src=proj_w; dst=projT; K=128; N=128; }
  else if(idx < 131072){ idx -= 65536; src=fc1_w; dst=fc1T; K=128; N=512; }
  else { idx -= 131072; src=fc2_w; dst=fc2T; K=512; N=128; }
  int n = idx % N, k = idx / N;
  dst[(size_t)n*K + k] = f2b(src[idx]);
}

// ---------------- depthwise 3x3 conv + bias + residual -> channel-last fp32 ----------------
__global__ __launch_bounds__(256) void conv_kernel(const float* __restrict__ x,
                                                   const float* __restrict__ cw,
                                                   const float* __restrict__ cb,
                                                   float* __restrict__ xt){
  __shared__ float tile[16][132];
  int blk = blockIdx.x;              // ((b*8 + cg)*128 + h)
  int h = blk & 127; int t = blk >> 7;
  int cg = t & 7;    int b = t >> 3;
  int w4 = threadIdx.x & 31;
  int ci = threadIdx.x >> 5;
  int w0 = w4*4;
#pragma unroll
  for(int cc=0; cc<2; cc++){
    int c = cg*16 + ci*2 + cc;
    const float* xp = x + ((size_t)(b*Cc + c))*HW;
    float wg[9];
#pragma unroll
    for(int i=0;i<9;i++) wg[i] = cw[c*9+i];
    float4 rowv[3]; float lf[3], rt[3];
#pragma unroll
    for(int r=0;r<3;r++){
      int hh = h-1+r;
      float4 v = {0.f,0.f,0.f,0.f};
      if(hh>=0 && hh<Hh) v = *(const float4*)(xp + hh*Wl + w0);
      rowv[r] = v;
      float l = __shfl_up(v.w, 1, 32);
      float rr = __shfl_down(v.x, 1, 32);
      lf[r] = (w4==0)  ? 0.f : l;
      rt[r] = (w4==31) ? 0.f : rr;
    }
    float acc0 = cb[c], acc1 = cb[c], acc2 = cb[c], acc3 = cb[c];
#pragma unroll
    for(int r=0;r<3;r++){
      float4 v = rowv[r];
      acc0 += wg[r*3+0]*lf[r] + wg[r*3+1]*v.x + wg[r*3+2]*v.y;
      acc1 += wg[r*3+0]*v.x   + wg[r*3+1]*v.y + wg[r*3+2]*v.z;
      acc2 += wg[r*3+0]*v.y   + wg[r*3+1]*v.z + wg[r*3+2]*v.w;
      acc3 += wg[r*3+0]*v.z   + wg[r*3+1]*v.w + wg[r*3+2]*rt[r];
    }
    acc0 += rowv[1].x; acc1 += rowv[1].y; acc2 += rowv[1].z; acc3 += rowv[1].w;
    float4 o = {acc0, acc1, acc2, acc3};
    *(float4*)&tile[ci*2+cc][w0] = o;
  }
  __syncthreads();
  const size_t obase = ((size_t)b*HW + (size_t)h*Wl)*Cc + cg*16;
#pragma unroll
  for(int i=0;i<8;i++){
    int idx = i*256 + threadIdx.x;
    int c2 = idx & 15, w2 = idx >> 4;
    xt[obase + (size_t)w2*Cc + c2] = tile[c2][w2];
  }
}

// ---------------- LayerNorm over C=128, one wave per token ----------------
__global__ __launch_bounds__(256) void ln_kernel(const float* __restrict__ xt,
                                                 const float* __restrict__ wv,
                                                 const float* __restrict__ bv,
                                                 bf16* __restrict__ xn){
  int tok  = blockIdx.x*4 + (threadIdx.x>>6);
  int lane = threadIdx.x & 63;
  const float* row = xt + (size_t)tok*Cc;
  float v0 = row[lane], v1 = row[lane+64];
  float s = v0+v1;
#pragma unroll
  for(int off=32; off; off>>=1) s += __shfl_down(s, off, 64);
  s = __shfl(s, 0, 64);
  float m = s * (1.0f/128.0f);
  float d0 = v0-m, d1 = v1-m;
  float vs = d0*d0 + d1*d1;
#pragma unroll
  for(int off=32; off; off>>=1) vs += __shfl_down(vs, off, 64);
  vs = __shfl(vs, 0, 64);
  float rstd = rsqrtf(vs*(1.0f/128.0f) + 1e-5f);
  bf16* orow = xn + (size_t)tok*Cc;
  orow[lane]    = f2b(d0*rstd*wv[lane]    + bv[lane]);
  orow[lane+64] = f2b(d1*rstd*wv[lane+64] + bv[lane+64]);
}

// ---------------- MFMA bf16 GEMM (global_load_lds staging, dbuf, XCD swizzle) ----------------
// EPI 0: qkv -> scatter into 6 head-major attention buffers (outb = base of qL..vG)
// EPI 2: +bias, xt += ls*v
template<int EPI>
__global__ __launch_bounds__(256) void mfma_gemm(const bf16* __restrict__ A,
                                                 const bf16* __restrict__ Wt,
                                                 const float* __restrict__ bias,
                                                 bf16* __restrict__ outb,
                                                 float* __restrict__ xt,
                                                 const float* __restrict__ ls,
                                                 int N, int K){
  __shared__ short As[2][128*32];
  __shared__ short Bs[2][64*32];
  const int tid  = threadIdx.x;
  const int lane = tid & 63;
  const int w    = tid >> 6;

  // XCD-chunked swizzle: all n-blocks of one m-tile land on the same XCD (consecutive t)
  const int nwg = gridDim.x * gridDim.y;
  const int lin = blockIdx.y * gridDim.x + blockIdx.x;
  const int t   = (lin & 7) * (nwg >> 3) + (lin >> 3);
  const int m0  = (t / gridDim.x) * 128;
  const int n0  = (t % gridDim.x) * 64;

  // pre-swizzled global source addresses so linear LDS (= fragment order) is correct:
  // lidx -> row = (lidx>>6)*16 + (lidx&15), kchunk = (lidx>>4)&3
  const int l1 = tid + 256;
  const bf16* gA0 = A  + (size_t)(m0 + ((tid>>6)<<4) + (tid&15))*K + (((tid>>4)&3)<<3);
  const bf16* gA1 = A  + (size_t)(m0 + ((l1 >>6)<<4) + (l1 &15))*K + (((l1 >>4)&3)<<3);
  const bf16* gB  = Wt + (size_t)(n0 + ((tid>>6)<<4) + (tid&15))*K + (((tid>>4)&3)<<3);
  // wave-uniform LDS dest bases (shorts)
  const int ldsA0 = w*512;           // chunk 0: lidx = w*64+lane
  const int ldsA1 = 2048 + w*512;    // chunk 1: lidx = 256 + w*64+lane
  const int ldsB  = w*512;

  floatx4 acc[4][2];
#pragma unroll
  for(int i=0;i<4;i++)
#pragma unroll
    for(int j=0;j<2;j++) acc[i][j] = (floatx4){0.f,0.f,0.f,0.f};

  const int nk = K >> 5;
  // prologue: stage k-step 0 into buf 0
  GL16(gA0, &As[0][ldsA0]);
  GL16(gA1, &As[0][ldsA1]);
  GL16(gB , &Bs[0][ldsB ]);
  __syncthreads();

  int cur = 0;
  for(int it=0; it<nk; ++it){
    if(it+1 < nk){
      const int kn = (it+1) << 5;
      GL16(gA0 + kn, &As[cur^1][ldsA0]);
      GL16(gA1 + kn, &As[cur^1][ldsA1]);
      GL16(gB  + kn, &Bs[cur^1][ldsB ]);
    }
    short8 af[4], bfr[2];
#pragma unroll
    for(int mt=0;mt<4;mt++) af[mt] = *(short8*)&As[cur][(((w&1)*4+mt)*64 + lane)*8];
#pragma unroll
    for(int nt=0;nt<2;nt++) bfr[nt] = *(short8*)&Bs[cur][(((w>>1)*2+nt)*64 + lane)*8];
#pragma unroll
    for(int mt=0;mt<4;mt++)
#pragma unroll
      for(int nt=0;nt<2;nt++)
        acc[mt][nt] = __builtin_amdgcn_mfma_f32_16x16x32_bf16(af[mt], bfr[nt], acc[mt][nt], 0, 0, 0);
    __syncthreads();   // drains vmcnt (prefetch landed) + all waves done reading buf cur
    cur ^= 1;
  }

#pragma unroll
  for(int mt=0;mt<4;mt++){
#pragma unroll
    for(int nt=0;nt<2;nt++){
#pragma unroll
      for(int r=0;r<4;r++){
        int row = m0 + (w&1)*64 + mt*16 + ((lane>>4))*4 + r;
        int col = n0 + (w>>1)*32 + nt*16 + (lane&15);
        float v = acc[mt][nt][r];
        if(EPI==0){
          // scatter to attention layout: reg 0..5 = qL,qG,kL,kG,vL,vG
          int reg = col >> 6;
          int head = (col >> 4) & 3;
          int ch = col & 15;
          int b = row >> 14, h = (row >> 7) & 127, ww = row & 127;
          if(reg < 2) v *= QSCALE;   // fold softmax scale*log2e into q
          size_t didx;
          if(!(reg & 1)){
            int inst = ((b*16 + (h>>3))*16 + (ww>>3))*4 + head;
            int pos = (h&7)*8 + (ww&7);
            didx = ((size_t)inst*64 + pos)*16 + ch;
          } else {
            int inst = ((b*8 + (h&7))*8 + (ww&7))*4 + head;
            int pos = (h>>3)*16 + (ww>>3);
            didx = ((size_t)inst*256 + pos)*16 + ch;
          }
          outb[(size_t)reg*REG + didx] = f2b(v);
        } else if(EPI==2){
          v += bias[col];
          xt[(size_t)row*128 + col] += ls[col]*v;
        }
      }
    }
  }
}

// ---------------- fused LN2 + MLP + output transpose (v5) ----------------
// out[b][c][hw] = xt + ls2 * (gelu(LN(xt)@W1 + b1) @ W2 + b2)   (fp32, final)
// Block = 128 tokens, 4 waves (wave owns 32 rows). LN2 done in-register in the
// prologue (quads hold disjoint col ranges -> 2 shfl_xor row reduction).
// Main loop: 16 chunks of 32, dbuf weight staging via global_load_lds, 1 barrier/chunk.
// Epilogue: per-16-col chunk LDS transpose (reuses W1 region) -> coalesced fp32 out.
__global__ __launch_bounds__(256) void fused_mlp(const float* __restrict__ xt,  // residual [NT][128] fp32
                                                 const bf16* __restrict__ W1,   // fc1T [512][128]
                                                 const float* __restrict__ b1,
                                                 const bf16* __restrict__ W2,   // fc2T [128][512]
                                                 const float* __restrict__ b2,
                                                 const float* __restrict__ nw,  // norm2_w
                                                 const float* __restrict__ nb,  // norm2_b
                                                 const float* __restrict__ ls,  // ls2
                                                 float* __restrict__ out){
  extern __shared__ short lds[];
  // layout (shorts): W1s[2][4096] | W2s[2][4096] | hs[4][1280]
  const int W1OFF = 0, W2OFF = 8192, HSOFF = 16384;
  const int tid = threadIdx.x, lane = tid & 63, w = tid >> 6;
  const int n16 = lane & 15, quad = lane >> 4;
  const int lin = blockIdx.x;
  const int t = (lin & 7)*128 + (lin >> 3);   // 1024 blocks, XCD-chunked
  const int mw = t*128 + w*32;

  // stage W1/W2 chunk nc (32 n1) into buffer buf. Frag layout: [fid][lane*8].
  auto stage = [&](int nc, int buf){
    const bf16* W1c = W1 + (size_t)nc*32*128;
#pragma unroll
    for(int p=0;p<2;p++){
      int fid = p*4 + w;                      // wave-uniform 0..7
      int nt = fid >> 2, ks = fid & 3;
      GL16(W1c + (size_t)(nt*16 + n16)*128 + ks*32 + quad*8, &lds[W1OFF + buf*4096 + fid*512]);
      GL16(W2 + (size_t)(fid*16 + n16)*512 + nc*32 + quad*8, &lds[W2OFF + buf*4096 + fid*512]);
    }
  };

  stage(0, 0);   // issue first chunk's weight loads; LN prologue hides the latency

  // ---- LN2 prologue: normalize this wave's 32 rows from xt into bf16 A-frags ----
  float wreg[4][8], breg[4][8];
#pragma unroll
  for(int ks=0;ks<4;ks++){
    *(float4*)&wreg[ks][0] = *(const float4*)(nw + ks*32 + quad*8);
    *(float4*)&wreg[ks][4] = *(const float4*)(nw + ks*32 + quad*8 + 4);
    *(float4*)&breg[ks][0] = *(const float4*)(nb + ks*32 + quad*8);
    *(float4*)&breg[ks][4] = *(const float4*)(nb + ks*32 + quad*8 + 4);
  }
  short8 areg[2][4];
#pragma unroll
  for(int mt=0;mt<2;mt++){
    const float* xr = xt + (size_t)(mw + mt*16 + n16)*128;
    float av[4][8]; float s = 0.f, qs = 0.f;
#pragma unroll
    for(int ks=0;ks<4;ks++){
      *(float4*)&av[ks][0] = *(const float4*)(xr + ks*32 + quad*8);
      *(float4*)&av[ks][4] = *(const float4*)(xr + ks*32 + quad*8 + 4);
#pragma unroll
      for(int j=0;j<8;j++){ s += av[ks][j]; qs += av[ks][j]*av[ks][j]; }
    }
    // row is spread over the 4 quads (lane bits 4,5) -> 2-step butterfly
    s  += __shfl_xor(s, 16, 64);  s  += __shfl_xor(s, 32, 64);
    qs += __shfl_xor(qs, 16, 64); qs += __shfl_xor(qs, 32, 64);
    float m = s*(1.0f/128.0f);
    float rstd = rsqrtf(qs*(1.0f/128.0f) - m*m + 1e-5f);
#pragma unroll
    for(int ks=0;ks<4;ks++){
      short8 t8;
#pragma unroll
      for(int j=0;j<8;j++){
        bf16 g = f2b((av[ks][j]-m)*rstd*wreg[ks][j] + breg[ks][j]);
        ((short*)&t8)[j] = *(short*)&g;
      }
      areg[mt][ks] = t8;
    }
  }

  floatx4 acc2[2][8];
#pragma unroll
  for(int i=0;i<2;i++)
#pragma unroll
    for(int j=0;j<8;j++) acc2[i][j] = (floatx4){0.f,0.f,0.f,0.f};

  short* hw = &lds[HSOFF + w*1280];   // [32 m][32 n + 8 pad]

  __syncthreads();                    // buf0 ready (barrier drains vmcnt)

  for(int nc=0; nc<16; ++nc){
    const int cur = nc & 1;
    if(nc+1 < 16) stage(nc+1, cur^1); // issue next chunk's loads BEFORE compute

    // GEMM1: h[32][32] = A[32][128] x W1c[128][32]
    const short* W1b = &lds[W1OFF + cur*4096];
    floatx4 acc1[2][2];
#pragma unroll
    for(int i=0;i<2;i++)
#pragma unroll
      for(int j=0;j<2;j++) acc1[i][j] = (floatx4){0.f,0.f,0.f,0.f};
#pragma unroll
    for(int ks=0;ks<4;ks++){
#pragma unroll
      for(int nt=0;nt<2;nt++){
        short8 bfr = *(const short8*)&W1b[(nt*4+ks)*512 + lane*8];
#pragma unroll
        for(int mt=0;mt<2;mt++)
          acc1[mt][nt] = __builtin_amdgcn_mfma_f32_16x16x32_bf16(areg[mt][ks], bfr, acc1[mt][nt], 0, 0, 0);
      }
    }

    // bias + GELU (tanh form, exp2 + fast rcp) -> bf16 -> wave-private LDS
#pragma unroll
    for(int nt=0;nt<2;nt++){
      float bb = b1[nc*32 + nt*16 + n16];
#pragma unroll
      for(int mt=0;mt<2;mt++){
#pragma unroll
        for(int r=0;r<4;r++){
          float v = acc1[mt][nt][r] + bb;
          float u = v*v;
          float e = EXP2(v*__fmaf_rn(u, 0.044715f, 1.0f)*(-2.3022127f));
          float g = v*__builtin_amdgcn_rcpf(1.0f + e);
          bf16 gb = f2b(g);
          hw[(mt*16 + quad*4 + r)*40 + nt*16 + n16] = *(short*)&gb;
        }
      }
    }

    // GEMM2 partial: acc2 += h[32][32] x W2c[32][128] (k=32 = one MFMA depth)
    const short* W2b = &lds[W2OFF + cur*4096];
    short8 ha[2];
#pragma unroll
    for(int mt=0;mt<2;mt++) ha[mt] = *(short8*)&hw[(mt*16 + n16)*40 + quad*8];
#pragma unroll
    for(int nt2=0;nt2<8;nt2++){
      short8 bf2 = *(const short8*)&W2b[nt2*512 + lane*8];
#pragma unroll
      for(int mt=0;mt<2;mt++)
        acc2[mt][nt2] = __builtin_amdgcn_mfma_f32_16x16x32_bf16(ha[mt], bf2, acc2[mt][nt2], 0, 0, 0);
    }

    __syncthreads();   // next buf staged (vmcnt drained) + all waves done reading cur
  }

  // ---- epilogue: f = xt + ls2*(acc2 + b2); LDS-transpose -> fp32 out[b][c][hw] ----
  // (last loop barrier guarantees W1 region is free to reuse)
  const int t128 = t*128;
  const int bI = t128 >> 14;          // / HW
  const int hw0 = t128 & (HW-1);
  float* op = out + (size_t)bI*Cc*HW + hw0;
  float* tlf = (float*)lds;           // [16 c][132 t] fp32 (8448B, inside W1 region)
  const int cI = tid >> 4, toff = (tid & 15)*8;
#pragma unroll
  for(int nt2=0;nt2<8;nt2++){
    int col = nt2*16 + n16;
    float bb = b2[col], lsv = ls[col];
#pragma unroll
    for(int mt=0;mt<2;mt++){
#pragma unroll
      for(int r=0;r<4;r++){
        int row = mw + mt*16 + quad*4 + r;
        float v = acc2[mt][nt2][r] + bb;
        tlf[n16*132 + (w*32 + mt*16 + quad*4 + r)] = xt[(size_t)row*128 + col] + lsv*v;
      }
    }
    __syncthreads();
    float4 v0 = *(float4*)&tlf[cI*132 + toff];
    float4 v1 = *(float4*)&tlf[cI*132 + toff + 4];
    *(float4*)&op[(size_t)(nt2*16 + cI)*HW + toff]     = v0;
    *(float4*)&op[(size_t)(nt2*16 + cI)*HW + toff + 4] = v1;
    __syncthreads();
  }
}

// ---------------- local attention: blk = winid*4 + head, L=64 ----------------
// q pre-scaled by QSCALE -> base-2 softmax with max subtraction.
__global__ __launch_bounds__(256) void attn_local2(const bf16* __restrict__ qL,
                                                   const bf16* __restrict__ kL,
                                                   const bf16* __restrict__ vL,
                                                   bf16* __restrict__ a){
  __shared__ short vt[16*72];      // V^T [16 ch][64 tok + 8 pad]
  __shared__ short pb[4][16*72];   // per-wave P
  const int tid = threadIdx.x;
  const int w = tid >> 6, lane = tid & 63;
  const int n16 = lane & 15, quad = lane >> 4;
  const int blk = blockIdx.x;
  const int head = blk & 3, winid = blk >> 2;
  const bf16* Qb = qL + (size_t)blk*1024;
  const bf16* Kb = kL + (size_t)blk*1024;
  const bf16* Vb = vL + (size_t)blk*1024;

  if(tid < 128){
    int tok = tid >> 1, u = tid & 1;
    short8 v = *(const short8*)(Vb + tok*16 + u*8);
#pragma unroll
    for(int i=0;i<8;i++) vt[(u*8+i)*72 + tok] = ((short*)&v)[i];
  }
  __syncthreads();

  const int qt = w;
  short8 qf = {0,0,0,0,0,0,0,0};
  if(quad < 2) qf = *(const short8*)(Qb + (qt*16+n16)*16 + quad*8);

  floatx4 sf[4];
#pragma unroll
  for(int kt=0; kt<4; kt++){
    short8 kf = {0,0,0,0,0,0,0,0};
    if(quad < 2) kf = *(const short8*)(Kb + (kt*16+n16)*16 + quad*8);
    floatx4 z = (floatx4){0.f,0.f,0.f,0.f};
    sf[kt] = __builtin_amdgcn_mfma_f32_16x16x32_bf16(qf, kf, z, 0, 0, 0);
  }

  float mx[4] = {-1e30f,-1e30f,-1e30f,-1e30f};
#pragma unroll
  for(int kt=0; kt<4; kt++)
#pragma unroll
    for(int r=0;r<4;r++) mx[r] = fmaxf(mx[r], sf[kt][r]);
#pragma unroll
  for(int r=0;r<4;r++){
    mx[r] = fmaxf(mx[r], __shfl_xor(mx[r], 1, 64));
    mx[r] = fmaxf(mx[r], __shfl_xor(mx[r], 2, 64));
    mx[r] = fmaxf(mx[r], __shfl_xor(mx[r], 4, 64));
    mx[r] = fmaxf(mx[r], __shfl_xor(mx[r], 8, 64));
    mx[r] = -mx[r];
  }
  float l[4] = {0.f,0.f,0.f,0.f};
#pragma unroll
  for(int kt=0; kt<4; kt++){
#pragma unroll
    for(int r=0;r<4;r++){
      float p = EXP2(sf[kt][r] + mx[r]);
      l[r] += p;
      bf16 pbv = f2b(p);
      pb[w][(quad*4+r)*72 + kt*16 + n16] = *(short*)&pbv;
    }
  }
#pragma unroll
  for(int r=0;r<4;r++){
    l[r] += __shfl_xor(l[r], 1, 64);
    l[r] += __shfl_xor(l[r], 2, 64);
    l[r] += __shfl_xor(l[r], 4, 64);
    l[r] += __shfl_xor(l[r], 8, 64);
  }

  floatx4 of = (floatx4){0.f,0.f,0.f,0.f};
#pragma unroll
  for(int kb=0; kb<2; kb++){
    short8 pf = *(short8*)&pb[w][n16*72 + kb*32 + quad*8];
    short8 vfb = *(short8*)&vt[n16*72 + kb*32 + quad*8];
    of = __builtin_amdgcn_mfma_f32_16x16x32_bf16(pf, vfb, of, 0, 0, 0);
  }

  const int wj = winid & 15, wi = (winid >> 4) & 15, b = winid >> 8;
  const int ooff = head*16;
#pragma unroll
  for(int r=0;r<4;r++){
    int pos = qt*16 + quad*4 + r;
    int h = wi*8 + (pos>>3), ww = wj*8 + (pos&7);
    size_t t = (size_t)b*HW + (size_t)h*Wl + ww;
    a[t*Cc + ooff + n16] = f2b(of[r] / l[r]);
  }
}

// ---------------- grid attention v2: swapped 32x32x16 QK^T, no-max base-2 softmax ----------------
// blk = ginst*4 + head, L=256. Each wave: 2 q-tiles of 32 rows; K in 2 chunks of 128.
__global__ __launch_bounds__(256) void attn_grid2(const bf16* __restrict__ qG,
                                                  const bf16* __restrict__ kG,
                                                  const bf16* __restrict__ vG,
                                                  bf16* __restrict__ a){
  __shared__ short vt[16*264];       // V^T [16 ch][256 tok + 8 pad]
  __shared__ short pb[4][32*136];    // per-wave P [32 q][128 k + 8 pad]
  const int tid = threadIdx.x;
  const int w = tid >> 6, lane = tid & 63;
  const int n16 = lane & 15, quad = lane >> 4;
  const int q32 = lane & 31, hb = lane >> 5;
  const int blk = blockIdx.x;
  const int head = blk & 3, ginst = blk >> 2;
  const bf16* Qb = qG + (size_t)blk*4096;
  const bf16* Kb = kG + (size_t)blk*4096;
  const bf16* Vb = vG + (size_t)blk*4096;

#pragma unroll
  for(int it=0; it<2; it++){
    int chunk = it*256 + tid;
    int tok = chunk >> 1, u = chunk & 1;
    short8 v = *(const short8*)(Vb + tok*16 + u*8);
#pragma unroll
    for(int i=0;i<8;i++) vt[(u*8+i)*264 + tok] = ((short*)&v)[i];
  }
  __syncthreads();

  const int sj = ginst & 7, si = (ginst >> 3) & 7, b = ginst >> 6;
  const int ooff = 64 + head*16;
  short* pbw = pb[w];
  const floatx16 Z16 = {0.f,0.f,0.f,0.f,0.f,0.f,0.f,0.f,0.f,0.f,0.f,0.f,0.f,0.f,0.f,0.f};

#pragma unroll
  for(int qi=0; qi<2; qi++){
    const int q0 = w*64 + qi*32;
    const short8 qf = *(const short8*)(Qb + (size_t)(q0 + q32)*16 + hb*8);
    float l_acc = 0.f;
    floatx4 of0 = (floatx4){0.f,0.f,0.f,0.f};
    floatx4 of1 = (floatx4){0.f,0.f,0.f,0.f};
#pragma unroll
    for(int kc=0; kc<2; kc++){
#pragma unroll
      for(int kt=0; kt<4; kt++){
        short8 kf = *(const short8*)(Kb + (size_t)(kc*128 + kt*32 + q32)*16 + hb*8);
        // swapped: D[k][q], col=lane&31=q, row k = (reg&3)+8*(reg>>2)+4*hb (+32*kt)
        floatx16 s = __builtin_amdgcn_mfma_f32_32x32x16_bf16(kf, qf, Z16, 0, 0, 0);
#pragma unroll
        for(int g=0; g<4; g++){
          float p0 = EXP2(s[4*g+0]);
          float p1 = EXP2(s[4*g+1]);
          float p2 = EXP2(s[4*g+2]);
          float p3 = EXP2(s[4*g+3]);
          l_acc += (p0+p1)+(p2+p3);
          short4v pk = { (short)__bfloat16_as_ushort(f2b(p0)),
                         (short)__bfloat16_as_ushort(f2b(p1)),
                         (short)__bfloat16_as_ushort(f2b(p2)),
                         (short)__bfloat16_as_ushort(f2b(p3)) };
          *(short4v*)&pbw[q32*136 + kt*32 + g*8 + hb*4] = pk;
        }
      }
      // PV partial accumulate over this 128-wide k-chunk
#pragma unroll
      for(int kb=0; kb<4; kb++){
        short8 vf  = *(short8*)&vt[n16*264 + kc*128 + kb*32 + quad*8];
        short8 pf0 = *(short8*)&pbw[n16*136 + kb*32 + quad*8];
        of0 = __builtin_amdgcn_mfma_f32_16x16x32_bf16(pf0, vf, of0, 0, 0, 0);
        short8 pf1 = *(short8*)&pbw[(16+n16)*136 + kb*32 + quad*8];
        of1 = __builtin_amdgcn_mfma_f32_16x16x32_bf16(pf1, vf, of1, 0, 0, 0);
      }
    }
    l_acc += __shfl_xor(l_acc, 32, 64);
#pragma unroll
    for(int hf=0; hf<2; hf++){
      floatx4 of = hf ? of1 : of0;
#pragma unroll
      for(int r=0;r<4;r++){
        float lr = __shfl(l_acc, hf*16 + quad*4 + r, 64);
        int pos = q0 + hf*16 + quad*4 + r;
        int h = (pos>>4)*8 + si, ww = (pos&15)*8 + sj;
        size_t t = (size_t)b*HW + (size_t)h*Wl + ww;
        a[t*Cc + ooff + n16] = f2b(of[r] / lr);
      }
    }
  }
}

extern "C" void kernel_launch(void* const* d_in, const int* in_sizes, int n_in,
                              void* d_out, int out_size, void* d_ws, size_t ws_size,
                              hipStream_t stream) {
  const float* x       = (const float*)d_in[0];
  const float* conv_w  = (const float*)d_in[1];
  const float* conv_b  = (const float*)d_in[2];
  const float* norm1_w = (const float*)d_in[3];
  const float* norm1_b = (const float*)d_in[4];
  const float* wqkv    = (const float*)d_in[5];
  const float* proj_w  = (const float*)d_in[6];
  const float* proj_b  = (const float*)d_in[7];
  const float* norm2_w = (const float*)d_in[8];
  const float* norm2_b = (const float*)d_in[9];
  const float* fc1_w   = (const float*)d_in[10];
  const float* fc1_b   = (const float*)d_in[11];
  const float* fc2_w   = (const float*)d_in[12];
  const float* fc2_b   = (const float*)d_in[13];
  const float* ls1     = (const float*)d_in[14];
  const float* ls2     = (const float*)d_in[15];
  float* out = (float*)d_out;

  char* ws = (char*)d_ws;
  float* xt = (float*)ws;                                        // 64 MiB fp32 residual
  bf16*  sh = (bf16*)(ws + (size_t)NT*Cc*4);                     // 32 MiB: xn -> a
  bf16*  qh = (bf16*)(ws + (size_t)NT*Cc*4 + (size_t)NT*Cc*2);   // 128 MiB: qkv buffers
  bf16*  wt = (bf16*)(ws + (size_t)NT*Cc*4 + (size_t)NT*Cc*2 + (size_t)NT*512*2);
  bf16* qkvT = wt;            // 384 x 128
  bf16* projT= wt + 49152;    // 128 x 128
  bf16* fc1T = wt + 65536;    // 512 x 128
  bf16* fc2T = wt + 131072;   // 128 x 512

  transpose_all<<<196608/256, 256, 0, stream>>>(wqkv, proj_w, fc1_w, fc2_w,
                                                qkvT, projT, fc1T, fc2T);
  conv_kernel<<<Bn*8*Hh, 256, 0, stream>>>(x, conv_w, conv_b, xt);
  ln_kernel<<<NT/4, 256, 0, stream>>>(xt, norm1_w, norm1_b, sh);
  // qkv GEMM scatters into qL,qG,kL,kG,vL,vG (6 x 16 MiB at qh)
  mfma_gemm<0><<<dim3(384/64, NT/128), 256, 0, stream>>>(sh, qkvT, nullptr, qh, nullptr, nullptr, 384, 128);
  attn_grid2<<<2048, 256, 0, stream>>>(qh + (size_t)1*REG, qh + (size_t)3*REG, qh + (size_t)5*REG, sh);
  attn_local2<<<8192, 256, 0, stream>>>(qh + (size_t)0*REG, qh + (size_t)2*REG, qh + (size_t)4*REG, sh);
  mfma_gemm<2><<<dim3(128/64, NT/128), 256, 0, stream>>>(sh, projT, proj_b, nullptr, xt, ls1, 128, 128);
  // fused LN2 + MLP + transpose: reads xt, writes final fp32 out directly
  fused_mlp<<<NT/128, 256, 43008, stream>>>(xt, fc1T, fc1_b, fc2T, fc2_b,
                                            norm2_w, norm2_b, ls2, out);
}